// Round 17
// baseline (195.965 us; speedup 1.0000x reference)
//
#include <hip/hip_runtime.h>

// Locally connected layer:
// out[b,o,h,w] = sum_{c,i,j} x[b,c,h+i,w+j] * W[o,c,h,w,i,j] + bias[o,h,w]
// x: [32,32,64,64] f32, W: [64,32,62,62,3,3] f32, bias: [64,62,62] f32
// out: [32,64,62,62] f32
//
// R17 = R16 pipeline with 1 o per wave and a 992-block grid.
// R16 post-mortem: occupancy was GRID-limited (496 blocks / 256 CU = 1.94
// blocks/CU = 7.75 waves/CU = the measured 21%), and the 2-o live set
// (~190 regs) never fit VGPR=116. 1 o/wave fixes both: 992 blocks ->
// ~15.5 waves/CU (4/SIMD, the VGPR cap), and live set ~110 fits 116.
//  - W: coalesced gll->LDS per wave (R10), depth-2 prefetch, 2 buffers,
//    18.4 KB/block. Top-of-loop WAITV(9) waits only on gll(c) issued 2
//    channels ago; gll(c+1) rides. FIFO-clean (R11 lesson).
//  - x: direct float4, 3-slot rotation interleaved with FMAs (L1-broadcast
//    across the block's 4 waves - same h).
//  - DPP halo 0x101 (R8), chunked XCD swizzle (R3), nontemporal stores,
//    plain launch_bounds (min-waves spills: R4/R8; (256,2) no-op: R15).

#define C_  32
#define B_  32
#define O_  64
#define H_  64
#define W_  64
#define OH_ 62
#define OW_ 62

typedef float vfloat2 __attribute__((ext_vector_type(2)));
typedef float vfloat4 __attribute__((ext_vector_type(4)));

#define GLL4(gaddr, laddr)                                                      \
    __builtin_amdgcn_global_load_lds(                                           \
        (const __attribute__((address_space(1))) void*)(gaddr),                 \
        (__attribute__((address_space(3))) void*)(laddr), 4, 0, 0)

// dst[lane] = src[lane+1] within each 16-lane row (validated R8)
__device__ __forceinline__ float dpp_nextlane(float v) {
    return __int_as_float(__builtin_amdgcn_update_dpp(
        0, __float_as_int(v), 0x101, 0xf, 0xf, true));
}

#define WAITV(n) do {                                                           \
        asm volatile("s_waitcnt vmcnt(" #n ")" ::: "memory");                   \
        __builtin_amdgcn_sched_barrier(0);                                      \
    } while (0)

__global__ __launch_bounds__(256)
void lcl_kernel(const float* __restrict__ x,
                const float* __restrict__ Wt,
                const float* __restrict__ bias,
                float* __restrict__ out) {
    // W rows: [2 buffers][4 waves][576 floats] = 18432 B -> LDS allows 8/CU
    __shared__ float ldsW[2][4][576];

    // ---- chunked XCD swizzle (hw: XCD = blockIdx.x % 8); 992 = 8 * 124
    const int nblk    = (O_ / 4) * OH_;              // 992
    const int i0      = blockIdx.x;
    const int logical = (i0 & 7) * (nblk >> 3) + (i0 >> 3);
    const int og      = logical & 15;                // o-quad (fast)
    const int h       = logical >> 4;                // 0..61

    const int wv_i = threadIdx.x >> 6;               // wave 0..3
    const int o    = (og << 2) + wv_i;
    const int lane = threadIdx.x & 63;
    const int wg   = lane & 15;                      // w0 = 4*wg
    const int bg   = lane >> 4;                      // b0 = 8*bg
    const int w0   = wg * 4;
    const int b0   = bg * 8;
    const bool full = (wg < 15);                     // wg15 stores only w=60,61

    float acc[8][4];
#pragma unroll
    for (int bi = 0; bi < 8; ++bi)
#pragma unroll
        for (int wi = 0; wi < 4; ++wi) acc[bi][wi] = 0.f;

    // W row base (floats): o*C*34596 + h*558
    const long wrow = (long)o * (C_ * 34596) + (long)h * 558;

    // x byte base for (b0, h, w0)
    const char* xb0 = (const char*)x + (unsigned)b0 * 524288u
                      + (unsigned)h * 256u + (unsigned)wg * 16u;

    // stage one 2232-B W row coalesced (9 gll dword; tail covers [1976,2232),
    // overlap [1976,2048) double-written with same data).
#define STAGE_W(buf, cidx) do {                                                 \
        const char* s_ = (const char*)(Wt + wrow + (long)(cidx) * 34596);       \
        char* d_ = (char*)&ldsW[buf][wv_i][0];                                  \
        _Pragma("unroll")                                                       \
        for (int k_ = 0; k_ < 8; ++k_)                                          \
            GLL4(s_ + k_ * 256 + lane * 4, d_ + k_ * 256);                      \
        GLL4(s_ + 1976 + lane * 4, d_ + 1976);                                  \
    } while (0)

    // lane's 36 W floats (9 ds_read_b128, 144-B lane stride = 2-way alias =
    // free per m136). wg=15 tail reads pad garbage, never stored.
#define DSREAD_W(buf) do {                                                      \
        const char* r_ = (const char*)&ldsW[buf][wv_i][0] + wg * 144;           \
        _Pragma("unroll")                                                       \
        for (int q_ = 0; q_ < 9; ++q_)                                          \
            wq[q_] = *reinterpret_cast<const vfloat4*>(r_ + q_ * 16);           \
    } while (0)

#define WQ(t) (wq[(t) >> 2][(t) & 3])

    // issue 3 float4 rows of batch b0+bi_ for channel cidx into slot s_
#define XLD(s_, cidx, bi_) do {                                                 \
        const char* p_ = xb0 + (unsigned)(bi_) * 524288u                        \
                         + (unsigned)(cidx) * 16384u;                           \
        xv##s_[0] = *reinterpret_cast<const float4*>(p_);                       \
        xv##s_[1] = *reinterpret_cast<const float4*>(p_ + 256);                 \
        xv##s_[2] = *reinterpret_cast<const float4*>(p_ + 512);                 \
    } while (0)

    // expand slot s_ via DPP halo, 36 FMAs into acc[bi_]
#define FMA1(s_, bi_) do {                                                      \
        float xr_[3][6];                                                        \
        _Pragma("unroll")                                                       \
        for (int r_ = 0; r_ < 3; ++r_) {                                        \
            xr_[r_][0] = xv##s_[r_].x; xr_[r_][1] = xv##s_[r_].y;               \
            xr_[r_][2] = xv##s_[r_].z; xr_[r_][3] = xv##s_[r_].w;               \
            xr_[r_][4] = dpp_nextlane(xv##s_[r_].x);                            \
            xr_[r_][5] = dpp_nextlane(xv##s_[r_].y);                            \
        }                                                                       \
        _Pragma("unroll")                                                       \
        for (int wi_ = 0; wi_ < 4; ++wi_)                                       \
        _Pragma("unroll")                                                       \
        for (int ii_ = 0; ii_ < 3; ++ii_)                                       \
        _Pragma("unroll")                                                       \
        for (int j_ = 0; j_ < 3; ++j_)                                          \
            acc[bi_][wi_] = fmaf(xr_[ii_][wi_ + j_],                            \
                                 WQ(wi_ * 9 + ii_ * 3 + j_), acc[bi_][wi_]);    \
    } while (0)

    vfloat4 wq[9];
    float4  xvA[3], xvB[3], xvC[3];

    // ---- prologue: depth-2 W prefetch (18 gll outstanding)
    STAGE_W(0, 0);
    STAGE_W(1, 1);

    for (int c = 0; c < C_; ++c) {
        // gll(c) landed iff <= 9 outstanding (only gll(c+1), issued one
        // channel ago, may remain).
        WAITV(9);
        DSREAD_W(c & 1);                  // 9 ds_read_b128 (compiler lgkm)
        XLD(A, c, 0);
        XLD(B, c, 1);
        __builtin_amdgcn_sched_barrier(0);
        XLD(C, c, 2); FMA1(A, 0);
        XLD(A, c, 3); FMA1(B, 1);
        XLD(B, c, 4); FMA1(C, 2);
        XLD(C, c, 5); FMA1(A, 3);
        XLD(A, c, 6); FMA1(B, 4);
        XLD(B, c, 7); FMA1(C, 5);
        __builtin_amdgcn_sched_barrier(0);
        {                                 // stage W(c+2): YOUNGEST VMEM.
            // Writes buf c&1, already consumed by THIS wave's ds_reads above
            // (per-wave private slot, program-ordered) - safe.
            const int cn = (c + 2 < C_) ? (c + 2) : (C_ - 1);
            STAGE_W((c + 2) & 1, cn);
        }
        __builtin_amdgcn_sched_barrier(0);
        FMA1(A, 6);
        FMA1(B, 7);
    }

    // ---- epilogue: bias + nontemporal float2 stores (8B-aligned)
    const float* brow = bias + ((long)o * OH_ + h) * OW_ + w0;
    float2 bv0 = *reinterpret_cast<const float2*>(brow);
    float2 bv1;
    if (full) bv1 = *reinterpret_cast<const float2*>(brow + 2);
    else { bv1.x = 0.f; bv1.y = 0.f; }

#pragma unroll
    for (int bi = 0; bi < 8; ++bi) {
        float* orow = out + (((long)(b0 + bi) * O_ + o) * OH_ + h) * OW_ + w0;
        vfloat2 s0; s0.x = acc[bi][0] + bv0.x; s0.y = acc[bi][1] + bv0.y;
        __builtin_nontemporal_store(s0, reinterpret_cast<vfloat2*>(orow));
        if (full) {
            vfloat2 s1; s1.x = acc[bi][2] + bv1.x; s1.y = acc[bi][3] + bv1.y;
            __builtin_nontemporal_store(s1, reinterpret_cast<vfloat2*>(orow) + 1);
        }
    }

#undef STAGE_W
#undef DSREAD_W
#undef WQ
#undef XLD
#undef FMA1
}

extern "C" void kernel_launch(void* const* d_in, const int* in_sizes, int n_in,
                              void* d_out, int out_size, void* d_ws, size_t ws_size,
                              hipStream_t stream) {
    const float* x    = (const float*)d_in[0];
    const float* Wt   = (const float*)d_in[1];
    const float* bias = (const float*)d_in[2];
    float* out        = (float*)d_out;

    dim3 grid((O_ / 4) * OH_);   // 992 blocks (16 o-quads x 62 h), swizzled
    dim3 block(256);
    lcl_kernel<<<grid, block, 0, stream>>>(x, Wt, bias, out);
}

// Round 18
// 193.517 us; speedup vs baseline: 1.0127x; 1.0127x over previous
//
#include <hip/hip_runtime.h>

// Locally connected layer:
// out[b,o,h,w] = sum_{c,i,j} x[b,c,h+i,w+j] * W[o,c,h,w,i,j] + bias[o,h,w]
// x: [32,32,64,64] f32, W: [64,32,62,62,3,3] f32, bias: [64,62,62] f32
// out: [32,64,62,62] f32
//
// R18 = R17 with W prefetch depth-3 over 4 LDS buffers (36864 B).
// R17 post-mortem: compiler's VGPR heuristic targets the LDS-allowed max
// occupancy (it can't see grid size). LDS 18.4 KB -> 8 blocks/CU target ->
// VGPR squeezed to 64 -> live set (~110) serialized -> 251 us. Evidence:
// LDS 36.9K->VGPR 116 (R16), 67K+->116-132 (R13/R14), 18.4K->64 (R17),
// 64-thread->64 (R12). Fix: size LDS to the 4-blocks/CU bucket (36864 B)
// so the cap is 128 and the allocator keeps wq/xv live. Grid supplies
// 3.875 blocks/CU <= 4, so no occupancy is lost. First round with BOTH
// VGPR ~116 AND ~15.5 waves/CU.
//  - Depth-3 is also FIFO-cleaner: WAITV(18) waits on a gll issued 3
//    channels ago (~2 channels of cover); gll(c+1),(c+2) ride.
//  - 1 o/wave, coalesced W gll->LDS (R10), barrier-free (R12), x direct
//    float4 3-slot rotation (L1-broadcast across the 4 same-h waves),
//    DPP halo 0x101 (R8), chunked XCD swizzle (R3), nontemporal stores.

#define C_  32
#define B_  32
#define O_  64
#define H_  64
#define W_  64
#define OH_ 62
#define OW_ 62

typedef float vfloat2 __attribute__((ext_vector_type(2)));
typedef float vfloat4 __attribute__((ext_vector_type(4)));

#define GLL4(gaddr, laddr)                                                      \
    __builtin_amdgcn_global_load_lds(                                           \
        (const __attribute__((address_space(1))) void*)(gaddr),                 \
        (__attribute__((address_space(3))) void*)(laddr), 4, 0, 0)

// dst[lane] = src[lane+1] within each 16-lane row (validated R8)
__device__ __forceinline__ float dpp_nextlane(float v) {
    return __int_as_float(__builtin_amdgcn_update_dpp(
        0, __float_as_int(v), 0x101, 0xf, 0xf, true));
}

#define WAITV(n) do {                                                           \
        asm volatile("s_waitcnt vmcnt(" #n ")" ::: "memory");                   \
        __builtin_amdgcn_sched_barrier(0);                                      \
    } while (0)

__global__ __launch_bounds__(256)
void lcl_kernel(const float* __restrict__ x,
                const float* __restrict__ Wt,
                const float* __restrict__ bias,
                float* __restrict__ out) {
    // W rows: [4 buffers][4 waves][576 floats] = 36864 B -> 4 blocks/CU
    // bucket -> compiler VGPR cap 128 (the point of this round).
    __shared__ float ldsW[4][4][576];

    // ---- chunked XCD swizzle (hw: XCD = blockIdx.x % 8); 992 = 8 * 124
    const int nblk    = (O_ / 4) * OH_;              // 992
    const int i0      = blockIdx.x;
    const int logical = (i0 & 7) * (nblk >> 3) + (i0 >> 3);
    const int og      = logical & 15;                // o-quad (fast)
    const int h       = logical >> 4;                // 0..61

    const int wv_i = threadIdx.x >> 6;               // wave 0..3
    const int o    = (og << 2) + wv_i;
    const int lane = threadIdx.x & 63;
    const int wg   = lane & 15;                      // w0 = 4*wg
    const int bg   = lane >> 4;                      // b0 = 8*bg
    const int w0   = wg * 4;
    const int b0   = bg * 8;
    const bool full = (wg < 15);                     // wg15 stores only w=60,61

    float acc[8][4];
#pragma unroll
    for (int bi = 0; bi < 8; ++bi)
#pragma unroll
        for (int wi = 0; wi < 4; ++wi) acc[bi][wi] = 0.f;

    // W row base (floats): o*C*34596 + h*558
    const long wrow = (long)o * (C_ * 34596) + (long)h * 558;

    // x byte base for (b0, h, w0)
    const char* xb0 = (const char*)x + (unsigned)b0 * 524288u
                      + (unsigned)h * 256u + (unsigned)wg * 16u;

    // stage one 2232-B W row coalesced (9 gll dword; tail covers [1976,2232),
    // overlap [1976,2048) double-written with same data).
#define STAGE_W(buf, cidx) do {                                                 \
        const char* s_ = (const char*)(Wt + wrow + (long)(cidx) * 34596);       \
        char* d_ = (char*)&ldsW[buf][wv_i][0];                                  \
        _Pragma("unroll")                                                       \
        for (int k_ = 0; k_ < 8; ++k_)                                          \
            GLL4(s_ + k_ * 256 + lane * 4, d_ + k_ * 256);                      \
        GLL4(s_ + 1976 + lane * 4, d_ + 1976);                                  \
    } while (0)

    // lane's 36 W floats (9 ds_read_b128, 144-B lane stride = 2-way alias =
    // free per m136). wg=15 tail reads pad garbage, never stored.
#define DSREAD_W(buf) do {                                                      \
        const char* r_ = (const char*)&ldsW[buf][wv_i][0] + wg * 144;           \
        _Pragma("unroll")                                                       \
        for (int q_ = 0; q_ < 9; ++q_)                                          \
            wq[q_] = *reinterpret_cast<const vfloat4*>(r_ + q_ * 16);           \
    } while (0)

#define WQ(t) (wq[(t) >> 2][(t) & 3])

    // issue 3 float4 rows of batch b0+bi_ for channel cidx into slot s_
#define XLD(s_, cidx, bi_) do {                                                 \
        const char* p_ = xb0 + (unsigned)(bi_) * 524288u                        \
                         + (unsigned)(cidx) * 16384u;                           \
        xv##s_[0] = *reinterpret_cast<const float4*>(p_);                       \
        xv##s_[1] = *reinterpret_cast<const float4*>(p_ + 256);                 \
        xv##s_[2] = *reinterpret_cast<const float4*>(p_ + 512);                 \
    } while (0)

    // expand slot s_ via DPP halo, 36 FMAs into acc[bi_]
#define FMA1(s_, bi_) do {                                                      \
        float xr_[3][6];                                                        \
        _Pragma("unroll")                                                       \
        for (int r_ = 0; r_ < 3; ++r_) {                                        \
            xr_[r_][0] = xv##s_[r_].x; xr_[r_][1] = xv##s_[r_].y;               \
            xr_[r_][2] = xv##s_[r_].z; xr_[r_][3] = xv##s_[r_].w;               \
            xr_[r_][4] = dpp_nextlane(xv##s_[r_].x);                            \
            xr_[r_][5] = dpp_nextlane(xv##s_[r_].y);                            \
        }                                                                       \
        _Pragma("unroll")                                                       \
        for (int wi_ = 0; wi_ < 4; ++wi_)                                       \
        _Pragma("unroll")                                                       \
        for (int ii_ = 0; ii_ < 3; ++ii_)                                       \
        _Pragma("unroll")                                                       \
        for (int j_ = 0; j_ < 3; ++j_)                                          \
            acc[bi_][wi_] = fmaf(xr_[ii_][wi_ + j_],                            \
                                 WQ(wi_ * 9 + ii_ * 3 + j_), acc[bi_][wi_]);    \
    } while (0)

    vfloat4 wq[9];
    float4  xvA[3], xvB[3], xvC[3];

    // ---- prologue: depth-3 W prefetch (27 gll outstanding)
    STAGE_W(0, 0);
    STAGE_W(1, 1);
    STAGE_W(2, 2);

    for (int c = 0; c < C_; ++c) {
        // gll(c) landed iff <= 18 outstanding (gll(c+1), gll(c+2) remain;
        // gll(c) was issued 3 channels ago -> wait is ~free).
        WAITV(18);
        DSREAD_W(c & 3);                  // 9 ds_read_b128 (compiler lgkm)
        XLD(A, c, 0);
        XLD(B, c, 1);
        __builtin_amdgcn_sched_barrier(0);
        XLD(C, c, 2); FMA1(A, 0);
        XLD(A, c, 3); FMA1(B, 1);
        XLD(B, c, 4); FMA1(C, 2);
        XLD(C, c, 5); FMA1(A, 3);
        XLD(A, c, 6); FMA1(B, 4);
        XLD(B, c, 7); FMA1(C, 5);
        __builtin_amdgcn_sched_barrier(0);
        {                                 // stage W(c+3): YOUNGEST VMEM
            const int cn = (c + 3 < C_) ? (c + 3) : (C_ - 1);
            STAGE_W((c + 3) & 3, cn);
        }
        __builtin_amdgcn_sched_barrier(0);
        FMA1(A, 6);
        FMA1(B, 7);
    }

    // ---- epilogue: bias + nontemporal float2 stores (8B-aligned)
    const float* brow = bias + ((long)o * OH_ + h) * OW_ + w0;
    float2 bv0 = *reinterpret_cast<const float2*>(brow);
    float2 bv1;
    if (full) bv1 = *reinterpret_cast<const float2*>(brow + 2);
    else { bv1.x = 0.f; bv1.y = 0.f; }

#pragma unroll
    for (int bi = 0; bi < 8; ++bi) {
        float* orow = out + (((long)(b0 + bi) * O_ + o) * OH_ + h) * OW_ + w0;
        vfloat2 s0; s0.x = acc[bi][0] + bv0.x; s0.y = acc[bi][1] + bv0.y;
        __builtin_nontemporal_store(s0, reinterpret_cast<vfloat2*>(orow));
        if (full) {
            vfloat2 s1; s1.x = acc[bi][2] + bv1.x; s1.y = acc[bi][3] + bv1.y;
            __builtin_nontemporal_store(s1, reinterpret_cast<vfloat2*>(orow) + 1);
        }
    }

#undef STAGE_W
#undef DSREAD_W
#undef WQ
#undef XLD
#undef FMA1
}

extern "C" void kernel_launch(void* const* d_in, const int* in_sizes, int n_in,
                              void* d_out, int out_size, void* d_ws, size_t ws_size,
                              hipStream_t stream) {
    const float* x    = (const float*)d_in[0];
    const float* Wt   = (const float*)d_in[1];
    const float* bias = (const float*)d_in[2];
    float* out        = (float*)d_out;

    dim3 grid((O_ / 4) * OH_);   // 992 blocks (16 o-quads x 62 h), swizzled
    dim3 block(256);
    lcl_kernel<<<grid, block, 0, stream>>>(x, Wt, bias, out);
}

// Round 19
// 192.576 us; speedup vs baseline: 1.0176x; 1.0049x over previous
//
#include <hip/hip_runtime.h>

// Locally connected layer:
// out[b,o,h,w] = sum_{c,i,j} x[b,c,h+i,w+j] * W[o,c,h,w,i,j] + bias[o,h,w]
// x: [32,32,64,64] f32, W: [64,32,62,62,3,3] f32, bias: [64,62,62] f32
// out: [32,64,62,62] f32
//
// R19 = R18 + __attribute__((amdgpu_waves_per_eu(4,4))).
// R18 post-mortem: the compiler's pressure heuristic squeezes VGPR to the
// smallest waves/EU bucket it can schedule into (64 regs = 8 waves/EU),
// serializing the xv rotation + wq liveness. LDS sizing does NOT steer it
// (R18 falsified that), and launch_bounds' min-waves only caps from above.
// amdgpu_waves_per_eu(4,4) pins the target: max 4 waves/EU -> scheduler may
// hold ~110 live regs (acc 32 + wq 36 + xv 36 + addr) within the 128 cap.
// Grid supplies 992 blocks = 3.875 blocks/CU * 4 waves ~ 4 waves/EU, so the
// max clause costs nothing. First config with BOTH full ILP AND 15.5
// waves/CU. Decisive counter: VGPR (64 -> ~100-128 = success).
//
// Validated pieces unchanged: 1 o/wave, coalesced W gll->LDS (R10), depth-3
// prefetch over 4 buffers (WAITV(18) waits on a 3-channel-old gll; FIFO-
// clean per R11), barrier-free (R12), x direct float4 3-slot rotation
// (L1-broadcast across 4 same-h waves), DPP halo 0x101 (R8), chunked XCD
// swizzle (R3), nontemporal stores.

#define C_  32
#define B_  32
#define O_  64
#define H_  64
#define W_  64
#define OH_ 62
#define OW_ 62

typedef float vfloat2 __attribute__((ext_vector_type(2)));
typedef float vfloat4 __attribute__((ext_vector_type(4)));

#define GLL4(gaddr, laddr)                                                      \
    __builtin_amdgcn_global_load_lds(                                           \
        (const __attribute__((address_space(1))) void*)(gaddr),                 \
        (__attribute__((address_space(3))) void*)(laddr), 4, 0, 0)

// dst[lane] = src[lane+1] within each 16-lane row (validated R8)
__device__ __forceinline__ float dpp_nextlane(float v) {
    return __int_as_float(__builtin_amdgcn_update_dpp(
        0, __float_as_int(v), 0x101, 0xf, 0xf, true));
}

#define WAITV(n) do {                                                           \
        asm volatile("s_waitcnt vmcnt(" #n ")" ::: "memory");                   \
        __builtin_amdgcn_sched_barrier(0);                                      \
    } while (0)

__global__ __launch_bounds__(256)
__attribute__((amdgpu_waves_per_eu(4, 4)))
void lcl_kernel(const float* __restrict__ x,
                const float* __restrict__ Wt,
                const float* __restrict__ bias,
                float* __restrict__ out) {
    // W rows: [4 buffers][4 waves][576 floats] = 36864 B -> 4 blocks/CU
    __shared__ float ldsW[4][4][576];

    // ---- chunked XCD swizzle (hw: XCD = blockIdx.x % 8); 992 = 8 * 124
    const int nblk    = (O_ / 4) * OH_;              // 992
    const int i0      = blockIdx.x;
    const int logical = (i0 & 7) * (nblk >> 3) + (i0 >> 3);
    const int og      = logical & 15;                // o-quad (fast)
    const int h       = logical >> 4;                // 0..61

    const int wv_i = threadIdx.x >> 6;               // wave 0..3
    const int o    = (og << 2) + wv_i;
    const int lane = threadIdx.x & 63;
    const int wg   = lane & 15;                      // w0 = 4*wg
    const int bg   = lane >> 4;                      // b0 = 8*bg
    const int w0   = wg * 4;
    const int b0   = bg * 8;
    const bool full = (wg < 15);                     // wg15 stores only w=60,61

    float acc[8][4];
#pragma unroll
    for (int bi = 0; bi < 8; ++bi)
#pragma unroll
        for (int wi = 0; wi < 4; ++wi) acc[bi][wi] = 0.f;

    // W row base (floats): o*C*34596 + h*558
    const long wrow = (long)o * (C_ * 34596) + (long)h * 558;

    // x byte base for (b0, h, w0)
    const char* xb0 = (const char*)x + (unsigned)b0 * 524288u
                      + (unsigned)h * 256u + (unsigned)wg * 16u;

    // stage one 2232-B W row coalesced (9 gll dword; tail covers [1976,2232),
    // overlap [1976,2048) double-written with same data).
#define STAGE_W(buf, cidx) do {                                                 \
        const char* s_ = (const char*)(Wt + wrow + (long)(cidx) * 34596);       \
        char* d_ = (char*)&ldsW[buf][wv_i][0];                                  \
        _Pragma("unroll")                                                       \
        for (int k_ = 0; k_ < 8; ++k_)                                          \
            GLL4(s_ + k_ * 256 + lane * 4, d_ + k_ * 256);                      \
        GLL4(s_ + 1976 + lane * 4, d_ + 1976);                                  \
    } while (0)

    // lane's 36 W floats (9 ds_read_b128, 144-B lane stride = 2-way alias =
    // free per m136). wg=15 tail reads pad garbage, never stored.
#define DSREAD_W(buf) do {                                                      \
        const char* r_ = (const char*)&ldsW[buf][wv_i][0] + wg * 144;           \
        _Pragma("unroll")                                                       \
        for (int q_ = 0; q_ < 9; ++q_)                                          \
            wq[q_] = *reinterpret_cast<const vfloat4*>(r_ + q_ * 16);           \
    } while (0)

#define WQ(t) (wq[(t) >> 2][(t) & 3])

    // issue 3 float4 rows of batch b0+bi_ for channel cidx into slot s_
#define XLD(s_, cidx, bi_) do {                                                 \
        const char* p_ = xb0 + (unsigned)(bi_) * 524288u                        \
                         + (unsigned)(cidx) * 16384u;                           \
        xv##s_[0] = *reinterpret_cast<const float4*>(p_);                       \
        xv##s_[1] = *reinterpret_cast<const float4*>(p_ + 256);                 \
        xv##s_[2] = *reinterpret_cast<const float4*>(p_ + 512);                 \
    } while (0)

    // expand slot s_ via DPP halo, 36 FMAs into acc[bi_]
#define FMA1(s_, bi_) do {                                                      \
        float xr_[3][6];                                                        \
        _Pragma("unroll")                                                       \
        for (int r_ = 0; r_ < 3; ++r_) {                                        \
            xr_[r_][0] = xv##s_[r_].x; xr_[r_][1] = xv##s_[r_].y;               \
            xr_[r_][2] = xv##s_[r_].z; xr_[r_][3] = xv##s_[r_].w;               \
            xr_[r_][4] = dpp_nextlane(xv##s_[r_].x);                            \
            xr_[r_][5] = dpp_nextlane(xv##s_[r_].y);                            \
        }                                                                       \
        _Pragma("unroll")                                                       \
        for (int wi_ = 0; wi_ < 4; ++wi_)                                       \
        _Pragma("unroll")                                                       \
        for (int ii_ = 0; ii_ < 3; ++ii_)                                       \
        _Pragma("unroll")                                                       \
        for (int j_ = 0; j_ < 3; ++j_)                                          \
            acc[bi_][wi_] = fmaf(xr_[ii_][wi_ + j_],                            \
                                 WQ(wi_ * 9 + ii_ * 3 + j_), acc[bi_][wi_]);    \
    } while (0)

    vfloat4 wq[9];
    float4  xvA[3], xvB[3], xvC[3];

    // ---- prologue: depth-3 W prefetch (27 gll outstanding)
    STAGE_W(0, 0);
    STAGE_W(1, 1);
    STAGE_W(2, 2);

    for (int c = 0; c < C_; ++c) {
        // gll(c) landed iff <= 18 outstanding (gll(c+1), gll(c+2) remain;
        // gll(c) was issued 3 channels ago -> wait is ~free).
        WAITV(18);
        DSREAD_W(c & 3);                  // 9 ds_read_b128 (compiler lgkm)
        XLD(A, c, 0);
        XLD(B, c, 1);
        __builtin_amdgcn_sched_barrier(0);
        XLD(C, c, 2); FMA1(A, 0);
        XLD(A, c, 3); FMA1(B, 1);
        XLD(B, c, 4); FMA1(C, 2);
        XLD(C, c, 5); FMA1(A, 3);
        XLD(A, c, 6); FMA1(B, 4);
        XLD(B, c, 7); FMA1(C, 5);
        __builtin_amdgcn_sched_barrier(0);
        {                                 // stage W(c+3): YOUNGEST VMEM
            const int cn = (c + 3 < C_) ? (c + 3) : (C_ - 1);
            STAGE_W((c + 3) & 3, cn);
        }
        __builtin_amdgcn_sched_barrier(0);
        FMA1(A, 6);
        FMA1(B, 7);
    }

    // ---- epilogue: bias + nontemporal float2 stores (8B-aligned)
    const float* brow = bias + ((long)o * OH_ + h) * OW_ + w0;
    float2 bv0 = *reinterpret_cast<const float2*>(brow);
    float2 bv1;
    if (full) bv1 = *reinterpret_cast<const float2*>(brow + 2);
    else { bv1.x = 0.f; bv1.y = 0.f; }

#pragma unroll
    for (int bi = 0; bi < 8; ++bi) {
        float* orow = out + (((long)(b0 + bi) * O_ + o) * OH_ + h) * OW_ + w0;
        vfloat2 s0; s0.x = acc[bi][0] + bv0.x; s0.y = acc[bi][1] + bv0.y;
        __builtin_nontemporal_store(s0, reinterpret_cast<vfloat2*>(orow));
        if (full) {
            vfloat2 s1; s1.x = acc[bi][2] + bv1.x; s1.y = acc[bi][3] + bv1.y;
            __builtin_nontemporal_store(s1, reinterpret_cast<vfloat2*>(orow) + 1);
        }
    }

#undef STAGE_W
#undef DSREAD_W
#undef WQ
#undef XLD
#undef FMA1
}

extern "C" void kernel_launch(void* const* d_in, const int* in_sizes, int n_in,
                              void* d_out, int out_size, void* d_ws, size_t ws_size,
                              hipStream_t stream) {
    const float* x    = (const float*)d_in[0];
    const float* Wt   = (const float*)d_in[1];
    const float* bias = (const float*)d_in[2];
    float* out        = (float*)d_out;

    dim3 grid((O_ / 4) * OH_);   // 992 blocks (16 o-quads x 62 h), swizzled
    dim3 block(256);
    lcl_kernel<<<grid, block, 0, stream>>>(x, Wt, bias, out);
}

// Round 20
// 140.137 us; speedup vs baseline: 1.3984x; 1.3742x over previous
//
#include <hip/hip_runtime.h>

// Locally connected layer:
// out[b,o,h,w] = sum_{c,i,j} x[b,c,h+i,w+j] * W[o,c,h,w,i,j] + bias[o,h,w]
// x: [32,32,64,64] f32, W: [64,32,62,62,3,3] f32, bias: [64,62,62] f32
// out: [32,64,62,62] f32
//
// R20: forced-MLP + batch-split twins.
// R19 post-mortem: compiler SINKS loads to just before use inside a sched
// region (that's why VGPR=64 regardless of attributes) -> no MLP. Fix: pin
// ALL 12 x loads before a sched_barrier(0); results forced live across the
// fence -> allocator must hold ~120 regs and loads issue together.
// R16-vs-R17 lesson: x-traffic/CU dominates TLP -> keep 2 o's per wave.
// Grid to 15.5 waves/CU by splitting batches: twin blocks cover batches
// 0-15 / 16-31; twins are swizzle-adjacent -> same XCD -> dup W staging
// L2-hits. W: depth-2 gll->LDS (2 buffers, 36864 B = 4-blocks/CU bucket),
// WAITV(18) FIFO-clean; wq read per-o (36 regs, re-read for o1); STAGE at
// channel END (buffer fully consumed; gll(c+2) gets ~2 channels cover).
// DPP halo 0x101 (R8), chunked XCD swizzle (R3), nontemporal stores.

#define C_  32
#define B_  32
#define O_  64
#define H_  64
#define W_  64
#define OH_ 62
#define OW_ 62

typedef float vfloat2 __attribute__((ext_vector_type(2)));
typedef float vfloat4 __attribute__((ext_vector_type(4)));

#define GLL4(gaddr, laddr)                                                      \
    __builtin_amdgcn_global_load_lds(                                           \
        (const __attribute__((address_space(1))) void*)(gaddr),                 \
        (__attribute__((address_space(3))) void*)(laddr), 4, 0, 0)

// dst[lane] = src[lane+1] within each 16-lane row (validated R8)
__device__ __forceinline__ float dpp_nextlane(float v) {
    return __int_as_float(__builtin_amdgcn_update_dpp(
        0, __float_as_int(v), 0x101, 0xf, 0xf, true));
}

#define WAITV(n) do {                                                           \
        asm volatile("s_waitcnt vmcnt(" #n ")" ::: "memory");                   \
        __builtin_amdgcn_sched_barrier(0);                                      \
    } while (0)

#define FENCE() __builtin_amdgcn_sched_barrier(0)

__global__ __launch_bounds__(256)
void lcl_kernel(const float* __restrict__ x,
                const float* __restrict__ Wt,
                const float* __restrict__ bias,
                float* __restrict__ out) {
    // W rows: [2 buffers][4 waves][2 o's][576 floats] = 36864 B (4 blk/CU)
    __shared__ float ldsW[2][4][2][576];

    // ---- chunked XCD swizzle (hw: XCD = blockIdx.x % 8); 992 = 8 * 124
    const int i0      = blockIdx.x;
    const int logical = (i0 & 7) * 124 + (i0 >> 3);
    const int bhalf   = logical & 1;                 // twin: batches 0-15/16-31
    const int pair    = logical >> 1;                // 0..495
    const int og      = pair & 7;                    // o-octet (fast)
    const int h       = pair >> 3;                   // 0..61

    const int wv_i = threadIdx.x >> 6;               // wave 0..3
    const int o0   = (og << 3) + (wv_i << 1);        // this wave: o0, o0+1
    const int lane = threadIdx.x & 63;
    const int wg   = lane & 15;                      // w0 = 4*wg
    const int bg   = lane >> 4;                      // 4 batches per bg
    const int w0   = wg * 4;
    const int b0   = bhalf * 16 + bg * 4;
    const bool full = (wg < 15);                     // wg15 stores only w=60,61

    float acc0[4][4], acc1[4][4];
#pragma unroll
    for (int bi = 0; bi < 4; ++bi)
#pragma unroll
        for (int wi = 0; wi < 4; ++wi) { acc0[bi][wi] = 0.f; acc1[bi][wi] = 0.f; }

    // W row bases (floats): o*C*34596 + h*558
    const long wrow0 = (long)o0 * (C_ * 34596) + (long)h * 558;
    const long wrow1 = wrow0 + (long)C_ * 34596;     // o0+1

    // x byte base for (b0, h, w0)
    const char* xb0 = (const char*)x + (unsigned)b0 * 524288u
                      + (unsigned)h * 256u + (unsigned)wg * 16u;

    // stage both 2232-B W rows coalesced (2 x 9 gll dword; tail covers
    // [1976,2232), overlap [1976,2048) double-written with same data).
#define STAGE_W2(buf, cidx) do {                                                \
        const char* s0_ = (const char*)(Wt + wrow0 + (long)(cidx) * 34596);     \
        const char* s1_ = (const char*)(Wt + wrow1 + (long)(cidx) * 34596);     \
        char* d0_ = (char*)&ldsW[buf][wv_i][0][0];                              \
        char* d1_ = (char*)&ldsW[buf][wv_i][1][0];                              \
        _Pragma("unroll")                                                       \
        for (int k_ = 0; k_ < 8; ++k_)                                          \
            GLL4(s0_ + k_ * 256 + lane * 4, d0_ + k_ * 256);                    \
        GLL4(s0_ + 1976 + lane * 4, d0_ + 1976);                                \
        _Pragma("unroll")                                                       \
        for (int k_ = 0; k_ < 8; ++k_)                                          \
            GLL4(s1_ + k_ * 256 + lane * 4, d1_ + k_ * 256);                    \
        GLL4(s1_ + 1976 + lane * 4, d1_ + 1976);                                \
    } while (0)

    // lane's 36 W floats for o-slot oo_ (9 ds_read_b128; 144-B lane stride =
    // 2-way alias + 4-way bg broadcast = cheap). wg=15 reads pad, not stored.
#define DSREAD_W(buf, oo_) do {                                                 \
        const char* r_ = (const char*)&ldsW[buf][wv_i][oo_][0] + wg * 144;      \
        _Pragma("unroll")                                                       \
        for (int q_ = 0; q_ < 9; ++q_)                                          \
            wq[q_] = *reinterpret_cast<const vfloat4*>(r_ + q_ * 16);           \
    } while (0)

#define WQ(t) (wq[(t) >> 2][(t) & 3])

    // issue 3 float4 rows of batch b0+bi_ for channel cidx into slot s_
#define XLD(s_, cidx, bi_) do {                                                 \
        const char* p_ = xb0 + (unsigned)(bi_) * 524288u                        \
                         + (unsigned)(cidx) * 16384u;                           \
        xv##s_[0] = *reinterpret_cast<const float4*>(p_);                       \
        xv##s_[1] = *reinterpret_cast<const float4*>(p_ + 256);                 \
        xv##s_[2] = *reinterpret_cast<const float4*>(p_ + 512);                 \
    } while (0)

    // expand slot s_ via DPP halo, 36 FMAs into ACC[bi_]
#define FMA1(ACC, s_, bi_) do {                                                 \
        float xr_[3][6];                                                        \
        _Pragma("unroll")                                                       \
        for (int r_ = 0; r_ < 3; ++r_) {                                        \
            xr_[r_][0] = xv##s_[r_].x; xr_[r_][1] = xv##s_[r_].y;               \
            xr_[r_][2] = xv##s_[r_].z; xr_[r_][3] = xv##s_[r_].w;               \
            xr_[r_][4] = dpp_nextlane(xv##s_[r_].x);                            \
            xr_[r_][5] = dpp_nextlane(xv##s_[r_].y);                            \
        }                                                                       \
        _Pragma("unroll")                                                       \
        for (int wi_ = 0; wi_ < 4; ++wi_)                                       \
        _Pragma("unroll")                                                       \
        for (int ii_ = 0; ii_ < 3; ++ii_)                                       \
        _Pragma("unroll")                                                       \
        for (int j_ = 0; j_ < 3; ++j_)                                          \
            ACC[bi_][wi_] = fmaf(xr_[ii_][wi_ + j_],                            \
                                 WQ(wi_ * 9 + ii_ * 3 + j_), ACC[bi_][wi_]);    \
    } while (0)

    vfloat4 wq[9];
    float4  xvA[3], xvB[3], xvC[3], xvD[3];

    // ---- prologue: depth-2 W prefetch (36 gll outstanding)
    STAGE_W2(0, 0);
    STAGE_W2(1, 1);

    for (int c = 0; c < C_; ++c) {
        const int p = c & 1;
        // gll(c) landed iff <= 18 outstanding (only gll(c+1) remains).
        WAITV(18);
        // W for o0 + ALL x loads for this channel, PINNED before the fence:
        // results forced live (~120 regs) -> loads issue together (MLP).
        DSREAD_W(p, 0);
        XLD(A, c, 0);
        XLD(B, c, 1);
        XLD(C, c, 2);
        XLD(D, c, 3);
        FENCE();
        FMA1(acc0, A, 0);
        FMA1(acc0, B, 1);
        FMA1(acc0, C, 2);
        FMA1(acc0, D, 3);
        FENCE();
        DSREAD_W(p, 1);                   // wq := o1 row (same regs)
        FENCE();
        FMA1(acc1, A, 0);
        FMA1(acc1, B, 1);
        FMA1(acc1, C, 2);
        FMA1(acc1, D, 3);
        FENCE();
        {                                 // stage W(c+2): buffer p fully
            const int cn = (c + 2 < C_) ? (c + 2) : (C_ - 1);   // consumed
            STAGE_W2(p, cn);              // YOUNGEST VMEM; ~2 channels cover
        }
    }

    // ---- epilogue: bias + nontemporal float2 stores (8B-aligned), 2 o's
#pragma unroll
    for (int oo = 0; oo < 2; ++oo) {
        const int oc = o0 + oo;
        const float* brow = bias + ((long)oc * OH_ + h) * OW_ + w0;
        float2 bv0 = *reinterpret_cast<const float2*>(brow);
        float2 bv1;
        if (full) bv1 = *reinterpret_cast<const float2*>(brow + 2);
        else { bv1.x = 0.f; bv1.y = 0.f; }
#pragma unroll
        for (int bi = 0; bi < 4; ++bi) {
            const float* a_ = oo ? acc1[bi] : acc0[bi];
            float* orow = out + (((long)(b0 + bi) * O_ + oc) * OH_ + h) * OW_ + w0;
            vfloat2 s0; s0.x = a_[0] + bv0.x; s0.y = a_[1] + bv0.y;
            __builtin_nontemporal_store(s0, reinterpret_cast<vfloat2*>(orow));
            if (full) {
                vfloat2 s1; s1.x = a_[2] + bv1.x; s1.y = a_[3] + bv1.y;
                __builtin_nontemporal_store(s1, reinterpret_cast<vfloat2*>(orow) + 1);
            }
        }
    }

#undef STAGE_W2
#undef DSREAD_W
#undef WQ
#undef XLD
#undef FMA1
}

extern "C" void kernel_launch(void* const* d_in, const int* in_sizes, int n_in,
                              void* d_out, int out_size, void* d_ws, size_t ws_size,
                              hipStream_t stream) {
    const float* x    = (const float*)d_in[0];
    const float* Wt   = (const float*)d_in[1];
    const float* bias = (const float*)d_in[2];
    float* out        = (float*)d_out;

    dim3 grid(992);   // (62 h x 8 og x 2 batch-halves), XCD-swizzled
    dim3 block(256);
    lcl_kernel<<<grid, block, 0, stream>>>(x, Wt, bias, out);
}

// Round 21
// 140.078 us; speedup vs baseline: 1.3990x; 1.0004x over previous
//
#include <hip/hip_runtime.h>

// Locally connected layer:
// out[b,o,h,w] = sum_{c,i,j} x[b,c,h+i,w+j] * W[o,c,h,w,i,j] + bias[o,h,w]
// x: [32,32,64,64] f32, W: [64,32,62,62,3,3] f32, bias: [64,62,62] f32
// out: [32,64,62,62] f32
//
// R21 = R20 with the x pipeline rotated one channel: x loads for c+1 are
// issued at the END of channel c, BEFORE STAGE_W2(c+2).
// R20 post-mortem: STAGE at end put 18 fresh gll AHEAD of the next
// channel's x loads in the vmcnt FIFO -> every channel's first FMA drained
// a ~100cy-old HBM gll burst (~500-800 cy stall/channel). New order makes
// x the oldest VMEM of its consuming channel and gll always the youngest:
//   WAITV(30)  [retires exactly gll(c), staged 2 channels ago - free]
//   DSREAD o0 | FMA acc0 (waits x(c): issued end of c-1, ahead of all gll)
//   DSREAD o1 | FMA acc1 | XLD(c+1) | STAGE_W2(c+2)
// Queue invariant at channel top: gll(c) 18 + x(c) 12 + gll(c+1) 18 = 48.
// Validated pieces: pin-before-FENCE (R20: VGPR 64->104), batch-split twins
// (R20), 2 o's/wave, coalesced W gll->LDS (R10), barrier-free (R12), DPP
// halo 0x101 (R8), chunked XCD swizzle (R3), nontemporal stores.

#define C_  32
#define B_  32
#define O_  64
#define H_  64
#define W_  64
#define OH_ 62
#define OW_ 62

typedef float vfloat2 __attribute__((ext_vector_type(2)));
typedef float vfloat4 __attribute__((ext_vector_type(4)));

#define GLL4(gaddr, laddr)                                                      \
    __builtin_amdgcn_global_load_lds(                                           \
        (const __attribute__((address_space(1))) void*)(gaddr),                 \
        (__attribute__((address_space(3))) void*)(laddr), 4, 0, 0)

// dst[lane] = src[lane+1] within each 16-lane row (validated R8)
__device__ __forceinline__ float dpp_nextlane(float v) {
    return __int_as_float(__builtin_amdgcn_update_dpp(
        0, __float_as_int(v), 0x101, 0xf, 0xf, true));
}

#define WAITV(n) do {                                                           \
        asm volatile("s_waitcnt vmcnt(" #n ")" ::: "memory");                   \
        __builtin_amdgcn_sched_barrier(0);                                      \
    } while (0)

#define FENCE() __builtin_amdgcn_sched_barrier(0)

__global__ __launch_bounds__(256)
void lcl_kernel(const float* __restrict__ x,
                const float* __restrict__ Wt,
                const float* __restrict__ bias,
                float* __restrict__ out) {
    // W rows: [2 buffers][4 waves][2 o's][576 floats] = 36864 B (4 blk/CU)
    __shared__ float ldsW[2][4][2][576];

    // ---- chunked XCD swizzle (hw: XCD = blockIdx.x % 8); 992 = 8 * 124
    const int i0      = blockIdx.x;
    const int logical = (i0 & 7) * 124 + (i0 >> 3);
    const int bhalf   = logical & 1;                 // twin: batches 0-15/16-31
    const int pair    = logical >> 1;                // 0..495
    const int og      = pair & 7;                    // o-octet (fast)
    const int h       = pair >> 3;                   // 0..61

    const int wv_i = threadIdx.x >> 6;               // wave 0..3
    const int o0   = (og << 3) + (wv_i << 1);        // this wave: o0, o0+1
    const int lane = threadIdx.x & 63;
    const int wg   = lane & 15;                      // w0 = 4*wg
    const int bg   = lane >> 4;                      // 4 batches per bg
    const int w0   = wg * 4;
    const int b0   = bhalf * 16 + bg * 4;
    const bool full = (wg < 15);                     // wg15 stores only w=60,61

    float acc0[4][4], acc1[4][4];
#pragma unroll
    for (int bi = 0; bi < 4; ++bi)
#pragma unroll
        for (int wi = 0; wi < 4; ++wi) { acc0[bi][wi] = 0.f; acc1[bi][wi] = 0.f; }

    // W row bases (floats): o*C*34596 + h*558
    const long wrow0 = (long)o0 * (C_ * 34596) + (long)h * 558;
    const long wrow1 = wrow0 + (long)C_ * 34596;     // o0+1

    // x byte base for (b0, h, w0)
    const char* xb0 = (const char*)x + (unsigned)b0 * 524288u
                      + (unsigned)h * 256u + (unsigned)wg * 16u;

    // stage both 2232-B W rows coalesced (2 x 9 gll dword; tail covers
    // [1976,2232), overlap [1976,2048) double-written with same data).
#define STAGE_W2(buf, cidx) do {                                                \
        const char* s0_ = (const char*)(Wt + wrow0 + (long)(cidx) * 34596);     \
        const char* s1_ = (const char*)(Wt + wrow1 + (long)(cidx) * 34596);     \
        char* d0_ = (char*)&ldsW[buf][wv_i][0][0];                              \
        char* d1_ = (char*)&ldsW[buf][wv_i][1][0];                              \
        _Pragma("unroll")                                                       \
        for (int k_ = 0; k_ < 8; ++k_)                                          \
            GLL4(s0_ + k_ * 256 + lane * 4, d0_ + k_ * 256);                    \
        GLL4(s0_ + 1976 + lane * 4, d0_ + 1976);                                \
        _Pragma("unroll")                                                       \
        for (int k_ = 0; k_ < 8; ++k_)                                          \
            GLL4(s1_ + k_ * 256 + lane * 4, d1_ + k_ * 256);                    \
        GLL4(s1_ + 1976 + lane * 4, d1_ + 1976);                                \
    } while (0)

    // lane's 36 W floats for o-slot oo_ (9 ds_read_b128; 144-B lane stride =
    // 2-way alias + 4-way bg broadcast = cheap). wg=15 reads pad, not stored.
#define DSREAD_W(buf, oo_) do {                                                 \
        const char* r_ = (const char*)&ldsW[buf][wv_i][oo_][0] + wg * 144;      \
        _Pragma("unroll")                                                       \
        for (int q_ = 0; q_ < 9; ++q_)                                          \
            wq[q_] = *reinterpret_cast<const vfloat4*>(r_ + q_ * 16);           \
    } while (0)

#define WQ(t) (wq[(t) >> 2][(t) & 3])

    // issue 3 float4 rows of batch b0+bi_ for channel cidx into slot s_
#define XLD(s_, cidx, bi_) do {                                                 \
        const char* p_ = xb0 + (unsigned)(bi_) * 524288u                        \
                         + (unsigned)(cidx) * 16384u;                           \
        xv##s_[0] = *reinterpret_cast<const float4*>(p_);                       \
        xv##s_[1] = *reinterpret_cast<const float4*>(p_ + 256);                 \
        xv##s_[2] = *reinterpret_cast<const float4*>(p_ + 512);                 \
    } while (0)

    // expand slot s_ via DPP halo, 36 FMAs into ACC[bi_]
#define FMA1(ACC, s_, bi_) do {                                                 \
        float xr_[3][6];                                                        \
        _Pragma("unroll")                                                       \
        for (int r_ = 0; r_ < 3; ++r_) {                                        \
            xr_[r_][0] = xv##s_[r_].x; xr_[r_][1] = xv##s_[r_].y;               \
            xr_[r_][2] = xv##s_[r_].z; xr_[r_][3] = xv##s_[r_].w;               \
            xr_[r_][4] = dpp_nextlane(xv##s_[r_].x);                            \
            xr_[r_][5] = dpp_nextlane(xv##s_[r_].y);                            \
        }                                                                       \
        _Pragma("unroll")                                                       \
        for (int wi_ = 0; wi_ < 4; ++wi_)                                       \
        _Pragma("unroll")                                                       \
        for (int ii_ = 0; ii_ < 3; ++ii_)                                       \
        _Pragma("unroll")                                                       \
        for (int j_ = 0; j_ < 3; ++j_)                                          \
            ACC[bi_][wi_] = fmaf(xr_[ii_][wi_ + j_],                            \
                                 WQ(wi_ * 9 + ii_ * 3 + j_), ACC[bi_][wi_]);    \
    } while (0)

    vfloat4 wq[9];
    float4  xvA[3], xvB[3], xvC[3], xvD[3];

    // ---- prologue: depth-2 W prefetch, then x(0) as the oldest-next VMEM
    STAGE_W2(0, 0);
    STAGE_W2(1, 1);
    XLD(A, 0, 0);
    XLD(B, 0, 1);
    XLD(C, 0, 2);
    XLD(D, 0, 3);

    for (int c = 0; c < C_; ++c) {
        const int p = c & 1;
        // invariant: outstanding = gll(c) 18 + x(c) 12 + gll(c+1) 18 = 48.
        // vmcnt(30) retires exactly gll(c) (2 channels old -> ~free), so
        // buf p's data is in LDS before DSREAD below.
        WAITV(30);
        DSREAD_W(p, 0);                   // wq := o0 row
        FENCE();
        FMA1(acc0, A, 0);                 // waits x(c) only (oldest in queue)
        FMA1(acc0, B, 1);
        FMA1(acc0, C, 2);
        FMA1(acc0, D, 3);
        FENCE();
        DSREAD_W(p, 1);                   // wq := o1 row (same regs)
        FENCE();
        FMA1(acc1, A, 0);
        FMA1(acc1, B, 1);
        FMA1(acc1, C, 2);
        FMA1(acc1, D, 3);
        FENCE();
        if (c + 1 < C_) {                 // x(c+1): oldest VMEM of channel c+1
            XLD(A, c + 1, 0);
            XLD(B, c + 1, 1);
            XLD(C, c + 1, 2);
            XLD(D, c + 1, 3);
        }
        FENCE();
        {                                 // gll(c+2): YOUNGEST. Clamped dup at
            const int cn = (c + 2 < C_) ? (c + 2) : (C_ - 1);  // c=30,31 keeps
            STAGE_W2(p, cn);              // the count invariant; buf p was
        }                                 // fully ds_read above (no race).
    }

    // ---- epilogue: bias + nontemporal float2 stores (8B-aligned), 2 o's
#pragma unroll
    for (int oo = 0; oo < 2; ++oo) {
        const int oc = o0 + oo;
        const float* brow = bias + ((long)oc * OH_ + h) * OW_ + w0;
        float2 bv0 = *reinterpret_cast<const float2*>(brow);
        float2 bv1;
        if (full) bv1 = *reinterpret_cast<const float2*>(brow + 2);
        else { bv1.x = 0.f; bv1.y = 0.f; }
#pragma unroll
        for (int bi = 0; bi < 4; ++bi) {
            const float* a_ = oo ? acc1[bi] : acc0[bi];
            float* orow = out + (((long)(b0 + bi) * O_ + oc) * OH_ + h) * OW_ + w0;
            vfloat2 s0; s0.x = a_[0] + bv0.x; s0.y = a_[1] + bv0.y;
            __builtin_nontemporal_store(s0, reinterpret_cast<vfloat2*>(orow));
            if (full) {
                vfloat2 s1; s1.x = a_[2] + bv1.x; s1.y = a_[3] + bv1.y;
                __builtin_nontemporal_store(s1, reinterpret_cast<vfloat2*>(orow) + 1);
            }
        }
    }

#undef STAGE_W2
#undef DSREAD_W
#undef WQ
#undef XLD
#undef FMA1
}

extern "C" void kernel_launch(void* const* d_in, const int* in_sizes, int n_in,
                              void* d_out, int out_size, void* d_ws, size_t ws_size,
                              hipStream_t stream) {
    const float* x    = (const float*)d_in[0];
    const float* Wt   = (const float*)d_in[1];
    const float* bias = (const float*)d_in[2];
    float* out        = (float*)d_out;

    dim3 grid(992);   // (62 h x 8 og x 2 batch-halves), XCD-swizzled
    dim3 block(256);
    lcl_kernel<<<grid, block, 0, stream>>>(x, Wt, bias, out);
}